// Round 9
// baseline (230.314 us; speedup 1.0000x reference)
//
#include <hip/hip_runtime.h>

#define N_NODES 50000
#define N_EDGES 800000
#define N_FEAT 128
#define N_HID 128
#define N_CLS 40
#define BN_EPS 1e-5f

#define CSR_STRIDE 64   // padded CSR row stride; max degree ~40 (Poisson 16)
#define NXCD 8
#define P_NODES 6250    // nodes per XCD partition (50000/8)
#define CSR_B 1024      // CSR-build blocks
#define CHUNK_E 2048    // edges per work-queue chunk
#define N_CHUNK ((N_EDGES + CHUNK_E - 1) / CHUNK_E)  // 391 per partition
#define WPACK_B 84
#define XPACK_B 3125

typedef short bf16x8 __attribute__((ext_vector_type(8)));
typedef float f32x4 __attribute__((ext_vector_type(4)));

// RNE float->bf16 helpers
__device__ __forceinline__ unsigned bfpack(float a, float b) {
    unsigned ua = __float_as_uint(a), ub = __float_as_uint(b);
    ua = (ua + 0x7FFFu + ((ua >> 16) & 1u)) >> 16;
    ub = (ub + 0x7FFFu + ((ub >> 16) & 1u)) >> 16;
    return ua | (ub << 16);
}
__device__ __forceinline__ unsigned short bfr1(float a) {
    unsigned u = __float_as_uint(a);
    u = (u + 0x7FFFu + ((u >> 16) & 1u)) >> 16;
    return (unsigned short)u;
}
__device__ __forceinline__ float bflo(unsigned u) { return __uint_as_float(u << 16); }
__device__ __forceinline__ float bfhi(unsigned u) { return __uint_as_float(u & 0xFFFF0000u); }

// ---------------------------------------------------------------------------
// Fused CSR-build + prep, TRUE-XCD-partitioned via HW_REG_XCC_ID + per-
// partition work queues. A CSR block reads its actual XCD id (m09: returns
// 0-7 on MI355X) and serves partition p = xcc&7, pulling 2048-edge chunks
// from wq[p] until empty. Coverage holds for ANY block->XCD placement; the
// queue only affects balance. Every csr_pad/deg_i line is therefore written
// by exactly one XCD's L2 (~825 KB/XCD working set). Discriminates r6's
// residual 22 MB write-amp: mapping-mismatch (fixed here) vs intra-XCD
// eviction (unchanged here). nt reverted (r8: hint-only on gfx950, -4.5 us).
// ---------------------------------------------------------------------------
__global__ __launch_bounds__(256) void degprep_kernel(
    const int* __restrict__ src, const int* __restrict__ dst,
    int* __restrict__ deg_i, int* __restrict__ wq,
    unsigned short* __restrict__ csr_pad,
    const float* __restrict__ W1l, const float* __restrict__ W1r,
    const float* __restrict__ W2l, const float* __restrict__ W2r,
    const float* __restrict__ x, unsigned* __restrict__ WfA,
    unsigned* __restrict__ WfB, unsigned* __restrict__ x_bf16) {
    int b = blockIdx.x;
    int t = threadIdx.x;
    if (b < CSR_B) {
        // hwreg imm: id=20 (HW_REG_XCC_ID), offset=0, size=32 -> (31<<11)|20
        unsigned xcc = __builtin_amdgcn_s_getreg(63508);
        const int p = (int)(xcc & (NXCD - 1));
        const int plo = p * P_NODES;
        const int phi = plo + P_NODES;
        const int4* dst4 = (const int4*)dst;
        const int4* src4 = (const int4*)src;
        __shared__ int s_chunk;
        for (;;) {
            if (t == 0) s_chunk = atomicAdd(&wq[p], 1);
            __syncthreads();
            int base = s_chunk * CHUNK_E;
            __syncthreads();
            if (base >= N_EDGES) break;
#pragma unroll
            for (int off = 0; off < CHUNK_E; off += 1024) {
                int e = base + off + t * 4;
                if (e < N_EDGES) {
                    int4 d4 = dst4[e >> 2];
                    int4 s4 = src4[e >> 2];
                    if (d4.x >= plo && d4.x < phi) {
                        int r = atomicAdd(&deg_i[d4.x], 1);
                        if (r < CSR_STRIDE) csr_pad[d4.x * CSR_STRIDE + r] = (unsigned short)s4.x;
                    }
                    if (d4.y >= plo && d4.y < phi) {
                        int r = atomicAdd(&deg_i[d4.y], 1);
                        if (r < CSR_STRIDE) csr_pad[d4.y * CSR_STRIDE + r] = (unsigned short)s4.y;
                    }
                    if (d4.z >= plo && d4.z < phi) {
                        int r = atomicAdd(&deg_i[d4.z], 1);
                        if (r < CSR_STRIDE) csr_pad[d4.z * CSR_STRIDE + r] = (unsigned short)s4.z;
                    }
                    if (d4.w >= plo && d4.w < phi) {
                        int r = atomicAdd(&deg_i[d4.w], 1);
                        if (r < CSR_STRIDE) csr_pad[d4.w * CSR_STRIDE + r] = (unsigned short)s4.w;
                    }
                }
            }
        }
        return;
    }
    int i = (b - CSR_B) * 256 + t;
    if (b < CSR_B + WPACK_B) {
        if (i < 16384) {
            int f = i >> 8, r = i & 255;
            int lane = r >> 2, u = r & 3;
            int phase = f >> 5, kc = (f >> 3) & 3, nt = f & 7;
            int k0 = phase * 128 + kc * 32 + (lane >> 4) * 8 + u * 2;
            int n = nt * 16 + (lane & 15);
            float w0, w1;
            if (k0 < 128) {
                w0 = W1l[n * 128 + k0];
                w1 = W1l[n * 128 + k0 + 1];
            } else {
                w0 = W1r[n * 128 + k0 - 128];
                w1 = W1r[n * 128 + k0 - 127];
            }
            WfA[i] = bfpack(w0, w1);
        } else if (i < 21504) {
            int j = i - 16384;
            int f = j >> 8, r = j & 255;
            int lane = r >> 2, u = r & 3;
            int kc = f / 5, nt = f % 5;
            int k0 = kc * 32 + (lane >> 4) * 8 + u * 2;
            int n = nt * 16 + (lane & 15);
            float w0, w1;
            if (n < 40) {
                w0 = W2l[n * 128 + k0];
                w1 = W2l[n * 128 + k0 + 1];
            } else {
                w0 = W2r[(n - 40) * 128 + k0];
                w1 = W2r[(n - 40) * 128 + k0 + 1];
            }
            WfB[j] = bfpack(w0, w1);
        }
    } else {
        int j = (b - CSR_B - WPACK_B) * 256 + t;
        if (j < 800000) {
            const float4* xf = (const float4*)x;
            float4 a = xf[(size_t)j * 2];
            float4 bq = xf[(size_t)j * 2 + 1];
            uint4 o;
            o.x = bfpack(a.x, a.y);
            o.y = bfpack(a.z, a.w);
            o.z = bfpack(bq.x, bq.y);
            o.w = bfpack(bq.z, bq.w);
            ((uint4*)x_bf16)[j] = o;
        }
    }
}

// ---------------------------------------------------------------------------
// Gather-mean layer 1 (bf16 x): subgroup-per-node, shuffle-free, ILP-8.
// 16 lanes own a node; padded-CSR addressing (beg = gid*64, n = deg).
// ---------------------------------------------------------------------------
__global__ __launch_bounds__(256) void gather1_kernel(const unsigned short* __restrict__ csr_pad,
                                                      const int* __restrict__ deg_i,
                                                      const unsigned* __restrict__ x_bf16,
                                                      unsigned* __restrict__ agg1b) {
    int sg = threadIdx.x >> 4;
    int li = threadIdx.x & 15;
    int gid = blockIdx.x * 16 + sg;
    if (gid >= N_NODES) return;
    int n = min(deg_i[gid], CSR_STRIDE);
    int beg = gid * CSR_STRIDE;
    int end = beg + n;
    const uint4* xb = (const uint4*)x_bf16;
    float acc[8];
#pragma unroll
    for (int j = 0; j < 8; ++j) acc[j] = 0.f;

    int e = beg;
    for (; e + 7 < end; e += 8) {
        uint4 tv[8];
#pragma unroll
        for (int q = 0; q < 8; ++q) {
            int s = csr_pad[e + q];
            tv[q] = xb[(size_t)s * 16 + li];
        }
#pragma unroll
        for (int q = 0; q < 8; ++q) {
            acc[0] += bflo(tv[q].x); acc[1] += bfhi(tv[q].x);
            acc[2] += bflo(tv[q].y); acc[3] += bfhi(tv[q].y);
            acc[4] += bflo(tv[q].z); acc[5] += bfhi(tv[q].z);
            acc[6] += bflo(tv[q].w); acc[7] += bfhi(tv[q].w);
        }
    }
    if (e + 3 < end) {
        uint4 tv[4];
#pragma unroll
        for (int q = 0; q < 4; ++q) {
            int s = csr_pad[e + q];
            tv[q] = xb[(size_t)s * 16 + li];
        }
#pragma unroll
        for (int q = 0; q < 4; ++q) {
            acc[0] += bflo(tv[q].x); acc[1] += bfhi(tv[q].x);
            acc[2] += bflo(tv[q].y); acc[3] += bfhi(tv[q].y);
            acc[4] += bflo(tv[q].z); acc[5] += bfhi(tv[q].z);
            acc[6] += bflo(tv[q].w); acc[7] += bfhi(tv[q].w);
        }
        e += 4;
    }
    for (; e < end; ++e) {
        int s = csr_pad[e];
        uint4 t0 = xb[(size_t)s * 16 + li];
        acc[0] += bflo(t0.x); acc[1] += bfhi(t0.x);
        acc[2] += bflo(t0.y); acc[3] += bfhi(t0.y);
        acc[4] += bflo(t0.z); acc[5] += bfhi(t0.z);
        acc[6] += bflo(t0.w); acc[7] += bfhi(t0.w);
    }
    float inv = 1.0f / fmaxf((float)n, 1.0f);
    uint4 o;
    o.x = bfpack(acc[0] * inv, acc[1] * inv);
    o.y = bfpack(acc[2] * inv, acc[3] * inv);
    o.z = bfpack(acc[4] * inv, acc[5] * inv);
    o.w = bfpack(acc[6] * inv, acc[7] * inv);
    ((uint4*)agg1b)[(size_t)gid * 16 + li] = o;
}

// ---------------------------------------------------------------------------
// Fused GEMM1+GEMM2 via MFMA (bf16):
//   h = BN(ReLU(agg1 @ W1l^T + b1 + x @ W1r^T)) kept in LDS;
//   [z2 | p2] = h @ [W2l^T | W2r^T].
// ---------------------------------------------------------------------------
__global__ __launch_bounds__(256) void gemm_fused_kernel(
    const unsigned* __restrict__ agg1b, const unsigned* __restrict__ xb,
    const unsigned* __restrict__ WfA, const unsigned* __restrict__ WfB,
    const float* __restrict__ b1,
    const float* __restrict__ gamma, const float* __restrict__ beta,
    const float* __restrict__ rmean, const float* __restrict__ rvar,
    unsigned short* __restrict__ z2s, float* __restrict__ p2) {
    __shared__ unsigned Asu[64 * 68];
    const int t = threadIdx.x;
    const int wid = __builtin_amdgcn_readfirstlane(t >> 6);
    const int lane = t & 63;
    const int li = lane & 15;
    const int quad = lane >> 4;
    const int mbase = blockIdx.x * 64;

    f32x4 dacc[8];
#pragma unroll
    for (int nt = 0; nt < 8; ++nt) dacc[nt] = (f32x4){0.f, 0.f, 0.f, 0.f};

    for (int phase = 0; phase < 2; ++phase) {
        const unsigned* __restrict__ A = phase ? xb : agg1b;
        __syncthreads();
#pragma unroll
        for (int i = 0; i < 4; ++i) {
            int e = i * 256 + t;
            int row = e >> 4, seg = e & 15;
            int rr = mbase + row;
            rr = (rr < N_NODES) ? rr : N_NODES - 1;
            uint4 v = ((const uint4*)A)[(size_t)rr * 16 + seg];
            *(uint4*)&Asu[row * 68 + seg * 4] = v;
        }
        __syncthreads();
        bf16x8 af[4];
#pragma unroll
        for (int kc = 0; kc < 4; ++kc)
            af[kc] = *(const bf16x8*)&Asu[(wid * 16 + li) * 68 + kc * 16 + quad * 4];

        const unsigned* __restrict__ Wp = WfA + phase * 8192;
#pragma unroll
        for (int nt = 0; nt < 8; ++nt) {
#pragma unroll
            for (int kc = 0; kc < 4; ++kc) {
                bf16x8 bfr = *(const bf16x8*)(Wp + (size_t)(kc * 8 + nt) * 256 + lane * 4);
                dacc[nt] = __builtin_amdgcn_mfma_f32_16x16x32_bf16(af[kc], bfr, dacc[nt], 0, 0, 0);
            }
        }
    }

    // --- GEMM1 epilogue: bias + ReLU + BN, h (bf16) into LDS -------------
    __syncthreads();
    unsigned short* Hs = (unsigned short*)Asu;  // row stride 136 ushorts
#pragma unroll
    for (int nt = 0; nt < 8; ++nt) {
        int cg = nt * 16 + li;
        float sc = gamma[cg] * rsqrtf(rvar[cg] + BN_EPS);
        float sh = fmaf(-rmean[cg], sc, beta[cg]);
        float bb = b1[cg];
#pragma unroll
        for (int r = 0; r < 4; ++r) {
            int row = wid * 16 + quad * 4 + r;
            float pre = dacc[nt][r] + bb;
            Hs[row * 136 + cg] = bfr1(fmaf(fmaxf(pre, 0.f), sc, sh));
        }
    }
    __syncthreads();

    // --- GEMM2 -----------------------------------------------------------
    bf16x8 af2[4];
#pragma unroll
    for (int kc = 0; kc < 4; ++kc)
        af2[kc] = *(const bf16x8*)&Asu[(wid * 16 + li) * 68 + kc * 16 + quad * 4];

    f32x4 d2[5];
#pragma unroll
    for (int nt = 0; nt < 5; ++nt) d2[nt] = (f32x4){0.f, 0.f, 0.f, 0.f};
#pragma unroll
    for (int nt = 0; nt < 5; ++nt) {
#pragma unroll
        for (int kc = 0; kc < 4; ++kc) {
            bf16x8 bfr = *(const bf16x8*)(WfB + (size_t)(kc * 5 + nt) * 256 + lane * 4);
            d2[nt] = __builtin_amdgcn_mfma_f32_16x16x32_bf16(af2[kc], bfr, d2[nt], 0, 0, 0);
        }
    }

#pragma unroll
    for (int nt = 0; nt < 5; ++nt) {
        int cg = nt * 16 + li;
#pragma unroll
        for (int r = 0; r < 4; ++r) {
            int row = mbase + wid * 16 + quad * 4 + r;
            if (row < N_NODES) {
                float vv = d2[nt][r];
                if (cg < 40) z2s[(size_t)row * 40 + cg] = bfr1(vv);
                else p2[(size_t)row * 40 + (cg - 40)] = vv;
            }
        }
    }
}

// ---------------------------------------------------------------------------
// Gather layer 2 + final (bf16 z2): subgroup-per-node, shuffle-free, ILP-8.
// 10 lanes own a node; padded-CSR addressing.
// ---------------------------------------------------------------------------
__global__ __launch_bounds__(256) void gather2_kernel(const unsigned short* __restrict__ csr_pad,
                                                      const int* __restrict__ deg_i,
                                                      const unsigned short* __restrict__ z2s,
                                                      const float* __restrict__ p2,
                                                      const float* __restrict__ b2,
                                                      float* __restrict__ out) {
    int t = threadIdx.x;
    int sub = t / 10;
    int li = t - sub * 10;
    if (sub >= 25) return;
    int gid = blockIdx.x * 25 + sub;
    if (gid >= N_NODES) return;
    int n = min(deg_i[gid], CSR_STRIDE);
    int beg = gid * CSR_STRIDE;
    int end = beg + n;
    const uint2* z2 = (const uint2*)z2s;
    float4 acc = {0.f, 0.f, 0.f, 0.f};
    int e = beg;
    for (; e + 7 < end; e += 8) {
        uint2 tv[8];
#pragma unroll
        for (int q = 0; q < 8; ++q) {
            int s = csr_pad[e + q];
            tv[q] = z2[(size_t)s * 10 + li];
        }
#pragma unroll
        for (int q = 0; q < 8; ++q) {
            acc.x += bflo(tv[q].x); acc.y += bfhi(tv[q].x);
            acc.z += bflo(tv[q].y); acc.w += bfhi(tv[q].y);
        }
    }
    if (e + 3 < end) {
        uint2 tv[4];
#pragma unroll
        for (int q = 0; q < 4; ++q) {
            int s = csr_pad[e + q];
            tv[q] = z2[(size_t)s * 10 + li];
        }
#pragma unroll
        for (int q = 0; q < 4; ++q) {
            acc.x += bflo(tv[q].x); acc.y += bfhi(tv[q].x);
            acc.z += bflo(tv[q].y); acc.w += bfhi(tv[q].y);
        }
        e += 4;
    }
    for (; e < end; ++e) {
        int s = csr_pad[e];
        uint2 t0 = z2[(size_t)s * 10 + li];
        acc.x += bflo(t0.x); acc.y += bfhi(t0.x);
        acc.z += bflo(t0.y); acc.w += bfhi(t0.y);
    }
    float inv = 1.0f / fmaxf((float)n, 1.0f);
    float4 p = ((const float4*)p2)[(size_t)gid * 10 + li];
    float4 bb = ((const float4*)b2)[li];
    float4 r;
    r.x = fmaf(acc.x, inv, p.x + bb.x);
    r.y = fmaf(acc.y, inv, p.y + bb.y);
    r.z = fmaf(acc.z, inv, p.z + bb.z);
    r.w = fmaf(acc.w, inv, p.w + bb.w);
    ((float4*)out)[(size_t)gid * 10 + li] = r;
}

// ---------------------------------------------------------------------------
// Launch: 5 dispatches. ws layout (int units):
//   deg_i[50048] + wq[16]  <- memset region (50064 ints)
//   csr_pad ushort[50000*64] = 1,600,000 ints
//   WfA u32[16384], WfB u32[5120]
//   x_bf16 u32[3200000]
//   agg1b u32[50048*64]
//   z2s ushort[50048*40] + p2 f32[50048*40]
// ---------------------------------------------------------------------------
extern "C" void kernel_launch(void* const* d_in, const int* in_sizes, int n_in,
                              void* d_out, int out_size, void* d_ws, size_t ws_size,
                              hipStream_t stream) {
    const float* x     = (const float*)d_in[0];
    const int*   ei    = (const int*)d_in[1];
    const float* W1l   = (const float*)d_in[2];
    const float* b1    = (const float*)d_in[3];
    const float* W1r   = (const float*)d_in[4];
    const float* gamma = (const float*)d_in[5];
    const float* beta  = (const float*)d_in[6];
    const float* rmean = (const float*)d_in[7];
    const float* rvar  = (const float*)d_in[8];
    const float* W2l   = (const float*)d_in[9];
    const float* b2    = (const float*)d_in[10];
    const float* W2r   = (const float*)d_in[11];
    float* out = (float*)d_out;

    int* deg_i              = (int*)d_ws;
    int* wq                 = deg_i + 50048;
    unsigned short* csr_pad = (unsigned short*)(wq + 16);
    unsigned* WfA           = (unsigned*)(wq + 16 + 1600000);
    unsigned* WfB           = WfA + 16384;
    unsigned* x_bf16        = WfB + 5120;
    unsigned* agg1b         = x_bf16 + 3200000;
    unsigned short* z2s     = (unsigned short*)(agg1b + (size_t)50048 * 64);
    float* p2               = (float*)(z2s + (size_t)50048 * 40);

    const int* src = ei;
    const int* dst = ei + N_EDGES;

    hipMemsetAsync(deg_i, 0, (size_t)(50048 + 16) * sizeof(int), stream);

    degprep_kernel<<<CSR_B + WPACK_B + XPACK_B, 256, 0, stream>>>(
        src, dst, deg_i, wq, csr_pad, W1l, W1r, W2l, W2r, x, WfA, WfB, x_bf16);

    gather1_kernel<<<(N_NODES + 15) / 16, 256, 0, stream>>>(csr_pad, deg_i, x_bf16, agg1b);

    gemm_fused_kernel<<<(N_NODES + 63) / 64, 256, 0, stream>>>(
        agg1b, x_bf16, WfA, WfB, b1, gamma, beta, rmean, rvar, z2s, p2);

    gather2_kernel<<<(N_NODES + 24) / 25, 256, 0, stream>>>(csr_pad, deg_i, z2s, p2, b2, out);
}

// Round 10
// 195.490 us; speedup vs baseline: 1.1781x; 1.1781x over previous
//
#include <hip/hip_runtime.h>

#define N_NODES 50000
#define N_EDGES 800000
#define N_FEAT 128
#define N_HID 128
#define N_CLS 40
#define BN_EPS 1e-5f

#define CSR_STRIDE 64   // padded CSR row stride; max degree ~40 (Poisson 16)
#define NXCD 8
#define P_NODES 6250    // nodes per XCD partition (50000/8)
#define CSR_B 1024      // CSR-build blocks: 128 per partition
#define CSR_BO 128      // blocks per partition
#define WPACK_B 84
#define XPACK_B 3125

typedef short bf16x8 __attribute__((ext_vector_type(8)));
typedef float f32x4 __attribute__((ext_vector_type(4)));

// RNE float->bf16 helpers
__device__ __forceinline__ unsigned bfpack(float a, float b) {
    unsigned ua = __float_as_uint(a), ub = __float_as_uint(b);
    ua = (ua + 0x7FFFu + ((ua >> 16) & 1u)) >> 16;
    ub = (ub + 0x7FFFu + ((ub >> 16) & 1u)) >> 16;
    return ua | (ub << 16);
}
__device__ __forceinline__ unsigned short bfr1(float a) {
    unsigned u = __float_as_uint(a);
    u = (u + 0x7FFFu + ((u >> 16) & 1u)) >> 16;
    return (unsigned short)u;
}
__device__ __forceinline__ float bflo(unsigned u) { return __uint_as_float(u << 16); }
__device__ __forceinline__ float bfhi(unsigned u) { return __uint_as_float(u & 0xFFFF0000u); }

// ---------------------------------------------------------------------------
// Fused CSR-build + prep, XCD-partitioned (r6 structure, ILP-8 chains).
// CSR blocks [0,1024): partition p = b&7 (round-robin block->XCD), 128 blocks
// per partition scan the full edge list, keeping edges with dst in-range.
// r9 falsified mapping-mismatch; r6-r9 counters show degprep is LATENCY-bound
// on the atomic->store chain (1.9 TB/s, 4% VALU). So: 8 edges/thread/iter
// (2x int4 dst), ~1 kept atomic chain in flight per thread (2x r6), and
// src4 loads guarded by the keep mask (~59% of 4-edge groups skip the load).
// ---------------------------------------------------------------------------
__global__ __launch_bounds__(256) void degprep_kernel(
    const int* __restrict__ src, const int* __restrict__ dst,
    int* __restrict__ deg_i, unsigned short* __restrict__ csr_pad,
    const float* __restrict__ W1l, const float* __restrict__ W1r,
    const float* __restrict__ W2l, const float* __restrict__ W2r,
    const float* __restrict__ x, unsigned* __restrict__ WfA,
    unsigned* __restrict__ WfB, unsigned* __restrict__ x_bf16) {
    int b = blockIdx.x;
    int t = threadIdx.x;
    if (b < CSR_B) {
        const int p = b & (NXCD - 1);
        const int bo = b >> 3;
        const int plo = p * P_NODES;
        const int phi = plo + P_NODES;
        const int4* dst4 = (const int4*)dst;
        const int4* src4 = (const int4*)src;
        // chunks of 2048 edges per block-iteration (256 thr x 8 edges)
        for (int c = bo; c * 2048 < N_EDGES; c += CSR_BO) {
            int e = c * 2048 + t * 8;
            if (e < N_EDGES) {
                int i4 = e >> 2;
                int4 da = dst4[i4];
                int4 db = dst4[i4 + 1];
                bool ka0 = (da.x >= plo) && (da.x < phi);
                bool ka1 = (da.y >= plo) && (da.y < phi);
                bool ka2 = (da.z >= plo) && (da.z < phi);
                bool ka3 = (da.w >= plo) && (da.w < phi);
                bool kb0 = (db.x >= plo) && (db.x < phi);
                bool kb1 = (db.y >= plo) && (db.y < phi);
                bool kb2 = (db.z >= plo) && (db.z < phi);
                bool kb3 = (db.w >= plo) && (db.w < phi);
                int4 sa = {0, 0, 0, 0}, sb = {0, 0, 0, 0};
                if (ka0 | ka1 | ka2 | ka3) sa = src4[i4];
                if (kb0 | kb1 | kb2 | kb3) sb = src4[i4 + 1];
                if (ka0) { int r = atomicAdd(&deg_i[da.x], 1);
                    if (r < CSR_STRIDE) csr_pad[da.x * CSR_STRIDE + r] = (unsigned short)sa.x; }
                if (ka1) { int r = atomicAdd(&deg_i[da.y], 1);
                    if (r < CSR_STRIDE) csr_pad[da.y * CSR_STRIDE + r] = (unsigned short)sa.y; }
                if (ka2) { int r = atomicAdd(&deg_i[da.z], 1);
                    if (r < CSR_STRIDE) csr_pad[da.z * CSR_STRIDE + r] = (unsigned short)sa.z; }
                if (ka3) { int r = atomicAdd(&deg_i[da.w], 1);
                    if (r < CSR_STRIDE) csr_pad[da.w * CSR_STRIDE + r] = (unsigned short)sa.w; }
                if (kb0) { int r = atomicAdd(&deg_i[db.x], 1);
                    if (r < CSR_STRIDE) csr_pad[db.x * CSR_STRIDE + r] = (unsigned short)sb.x; }
                if (kb1) { int r = atomicAdd(&deg_i[db.y], 1);
                    if (r < CSR_STRIDE) csr_pad[db.y * CSR_STRIDE + r] = (unsigned short)sb.y; }
                if (kb2) { int r = atomicAdd(&deg_i[db.z], 1);
                    if (r < CSR_STRIDE) csr_pad[db.z * CSR_STRIDE + r] = (unsigned short)sb.z; }
                if (kb3) { int r = atomicAdd(&deg_i[db.w], 1);
                    if (r < CSR_STRIDE) csr_pad[db.w * CSR_STRIDE + r] = (unsigned short)sb.w; }
            }
        }
        return;
    }
    int i = (b - CSR_B) * 256 + t;
    if (b < CSR_B + WPACK_B) {
        if (i < 16384) {
            int f = i >> 8, r = i & 255;
            int lane = r >> 2, u = r & 3;
            int phase = f >> 5, kc = (f >> 3) & 3, nt = f & 7;
            int k0 = phase * 128 + kc * 32 + (lane >> 4) * 8 + u * 2;
            int n = nt * 16 + (lane & 15);
            float w0, w1;
            if (k0 < 128) {
                w0 = W1l[n * 128 + k0];
                w1 = W1l[n * 128 + k0 + 1];
            } else {
                w0 = W1r[n * 128 + k0 - 128];
                w1 = W1r[n * 128 + k0 - 127];
            }
            WfA[i] = bfpack(w0, w1);
        } else if (i < 21504) {
            int j = i - 16384;
            int f = j >> 8, r = j & 255;
            int lane = r >> 2, u = r & 3;
            int kc = f / 5, nt = f % 5;
            int k0 = kc * 32 + (lane >> 4) * 8 + u * 2;
            int n = nt * 16 + (lane & 15);
            float w0, w1;
            if (n < 40) {
                w0 = W2l[n * 128 + k0];
                w1 = W2l[n * 128 + k0 + 1];
            } else {
                w0 = W2r[(n - 40) * 128 + k0];
                w1 = W2r[(n - 40) * 128 + k0 + 1];
            }
            WfB[j] = bfpack(w0, w1);
        }
    } else {
        int j = (b - CSR_B - WPACK_B) * 256 + t;
        if (j < 800000) {
            const float4* xf = (const float4*)x;
            float4 a = xf[(size_t)j * 2];
            float4 bq = xf[(size_t)j * 2 + 1];
            uint4 o;
            o.x = bfpack(a.x, a.y);
            o.y = bfpack(a.z, a.w);
            o.z = bfpack(bq.x, bq.y);
            o.w = bfpack(bq.z, bq.w);
            ((uint4*)x_bf16)[j] = o;
        }
    }
}

// ---------------------------------------------------------------------------
// Gather-mean layer 1 (bf16 x): subgroup-per-node, shuffle-free, ILP-8.
// 16 lanes own a node; padded-CSR addressing (beg = gid*64, n = deg).
// ---------------------------------------------------------------------------
__global__ __launch_bounds__(256) void gather1_kernel(const unsigned short* __restrict__ csr_pad,
                                                      const int* __restrict__ deg_i,
                                                      const unsigned* __restrict__ x_bf16,
                                                      unsigned* __restrict__ agg1b) {
    int sg = threadIdx.x >> 4;
    int li = threadIdx.x & 15;
    int gid = blockIdx.x * 16 + sg;
    if (gid >= N_NODES) return;
    int n = min(deg_i[gid], CSR_STRIDE);
    int beg = gid * CSR_STRIDE;
    int end = beg + n;
    const uint4* xb = (const uint4*)x_bf16;
    float acc[8];
#pragma unroll
    for (int j = 0; j < 8; ++j) acc[j] = 0.f;

    int e = beg;
    for (; e + 7 < end; e += 8) {
        uint4 tv[8];
#pragma unroll
        for (int q = 0; q < 8; ++q) {
            int s = csr_pad[e + q];
            tv[q] = xb[(size_t)s * 16 + li];
        }
#pragma unroll
        for (int q = 0; q < 8; ++q) {
            acc[0] += bflo(tv[q].x); acc[1] += bfhi(tv[q].x);
            acc[2] += bflo(tv[q].y); acc[3] += bfhi(tv[q].y);
            acc[4] += bflo(tv[q].z); acc[5] += bfhi(tv[q].z);
            acc[6] += bflo(tv[q].w); acc[7] += bfhi(tv[q].w);
        }
    }
    if (e + 3 < end) {
        uint4 tv[4];
#pragma unroll
        for (int q = 0; q < 4; ++q) {
            int s = csr_pad[e + q];
            tv[q] = xb[(size_t)s * 16 + li];
        }
#pragma unroll
        for (int q = 0; q < 4; ++q) {
            acc[0] += bflo(tv[q].x); acc[1] += bfhi(tv[q].x);
            acc[2] += bflo(tv[q].y); acc[3] += bfhi(tv[q].y);
            acc[4] += bflo(tv[q].z); acc[5] += bfhi(tv[q].z);
            acc[6] += bflo(tv[q].w); acc[7] += bfhi(tv[q].w);
        }
        e += 4;
    }
    for (; e < end; ++e) {
        int s = csr_pad[e];
        uint4 t0 = xb[(size_t)s * 16 + li];
        acc[0] += bflo(t0.x); acc[1] += bfhi(t0.x);
        acc[2] += bflo(t0.y); acc[3] += bfhi(t0.y);
        acc[4] += bflo(t0.z); acc[5] += bfhi(t0.z);
        acc[6] += bflo(t0.w); acc[7] += bfhi(t0.w);
    }
    float inv = 1.0f / fmaxf((float)n, 1.0f);
    uint4 o;
    o.x = bfpack(acc[0] * inv, acc[1] * inv);
    o.y = bfpack(acc[2] * inv, acc[3] * inv);
    o.z = bfpack(acc[4] * inv, acc[5] * inv);
    o.w = bfpack(acc[6] * inv, acc[7] * inv);
    ((uint4*)agg1b)[(size_t)gid * 16 + li] = o;
}

// ---------------------------------------------------------------------------
// Fused GEMM1+GEMM2 via MFMA (bf16):
//   h = BN(ReLU(agg1 @ W1l^T + b1 + x @ W1r^T)) kept in LDS;
//   [z2 | p2] = h @ [W2l^T | W2r^T].
// ---------------------------------------------------------------------------
__global__ __launch_bounds__(256) void gemm_fused_kernel(
    const unsigned* __restrict__ agg1b, const unsigned* __restrict__ xb,
    const unsigned* __restrict__ WfA, const unsigned* __restrict__ WfB,
    const float* __restrict__ b1,
    const float* __restrict__ gamma, const float* __restrict__ beta,
    const float* __restrict__ rmean, const float* __restrict__ rvar,
    unsigned short* __restrict__ z2s, float* __restrict__ p2) {
    __shared__ unsigned Asu[64 * 68];
    const int t = threadIdx.x;
    const int wid = __builtin_amdgcn_readfirstlane(t >> 6);
    const int lane = t & 63;
    const int li = lane & 15;
    const int quad = lane >> 4;
    const int mbase = blockIdx.x * 64;

    f32x4 dacc[8];
#pragma unroll
    for (int nt = 0; nt < 8; ++nt) dacc[nt] = (f32x4){0.f, 0.f, 0.f, 0.f};

    for (int phase = 0; phase < 2; ++phase) {
        const unsigned* __restrict__ A = phase ? xb : agg1b;
        __syncthreads();
#pragma unroll
        for (int i = 0; i < 4; ++i) {
            int e = i * 256 + t;
            int row = e >> 4, seg = e & 15;
            int rr = mbase + row;
            rr = (rr < N_NODES) ? rr : N_NODES - 1;
            uint4 v = ((const uint4*)A)[(size_t)rr * 16 + seg];
            *(uint4*)&Asu[row * 68 + seg * 4] = v;
        }
        __syncthreads();
        bf16x8 af[4];
#pragma unroll
        for (int kc = 0; kc < 4; ++kc)
            af[kc] = *(const bf16x8*)&Asu[(wid * 16 + li) * 68 + kc * 16 + quad * 4];

        const unsigned* __restrict__ Wp = WfA + phase * 8192;
#pragma unroll
        for (int nt = 0; nt < 8; ++nt) {
#pragma unroll
            for (int kc = 0; kc < 4; ++kc) {
                bf16x8 bfr = *(const bf16x8*)(Wp + (size_t)(kc * 8 + nt) * 256 + lane * 4);
                dacc[nt] = __builtin_amdgcn_mfma_f32_16x16x32_bf16(af[kc], bfr, dacc[nt], 0, 0, 0);
            }
        }
    }

    // --- GEMM1 epilogue: bias + ReLU + BN, h (bf16) into LDS -------------
    __syncthreads();
    unsigned short* Hs = (unsigned short*)Asu;  // row stride 136 ushorts
#pragma unroll
    for (int nt = 0; nt < 8; ++nt) {
        int cg = nt * 16 + li;
        float sc = gamma[cg] * rsqrtf(rvar[cg] + BN_EPS);
        float sh = fmaf(-rmean[cg], sc, beta[cg]);
        float bb = b1[cg];
#pragma unroll
        for (int r = 0; r < 4; ++r) {
            int row = wid * 16 + quad * 4 + r;
            float pre = dacc[nt][r] + bb;
            Hs[row * 136 + cg] = bfr1(fmaf(fmaxf(pre, 0.f), sc, sh));
        }
    }
    __syncthreads();

    // --- GEMM2 -----------------------------------------------------------
    bf16x8 af2[4];
#pragma unroll
    for (int kc = 0; kc < 4; ++kc)
        af2[kc] = *(const bf16x8*)&Asu[(wid * 16 + li) * 68 + kc * 16 + quad * 4];

    f32x4 d2[5];
#pragma unroll
    for (int nt = 0; nt < 5; ++nt) d2[nt] = (f32x4){0.f, 0.f, 0.f, 0.f};
#pragma unroll
    for (int nt = 0; nt < 5; ++nt) {
#pragma unroll
        for (int kc = 0; kc < 4; ++kc) {
            bf16x8 bfr = *(const bf16x8*)(WfB + (size_t)(kc * 5 + nt) * 256 + lane * 4);
            d2[nt] = __builtin_amdgcn_mfma_f32_16x16x32_bf16(af2[kc], bfr, d2[nt], 0, 0, 0);
        }
    }

#pragma unroll
    for (int nt = 0; nt < 5; ++nt) {
        int cg = nt * 16 + li;
#pragma unroll
        for (int r = 0; r < 4; ++r) {
            int row = mbase + wid * 16 + quad * 4 + r;
            if (row < N_NODES) {
                float vv = d2[nt][r];
                if (cg < 40) z2s[(size_t)row * 40 + cg] = bfr1(vv);
                else p2[(size_t)row * 40 + (cg - 40)] = vv;
            }
        }
    }
}

// ---------------------------------------------------------------------------
// Gather layer 2 + final (bf16 z2): subgroup-per-node, shuffle-free, ILP-8.
// 10 lanes own a node; padded-CSR addressing.
// ---------------------------------------------------------------------------
__global__ __launch_bounds__(256) void gather2_kernel(const unsigned short* __restrict__ csr_pad,
                                                      const int* __restrict__ deg_i,
                                                      const unsigned short* __restrict__ z2s,
                                                      const float* __restrict__ p2,
                                                      const float* __restrict__ b2,
                                                      float* __restrict__ out) {
    int t = threadIdx.x;
    int sub = t / 10;
    int li = t - sub * 10;
    if (sub >= 25) return;
    int gid = blockIdx.x * 25 + sub;
    if (gid >= N_NODES) return;
    int n = min(deg_i[gid], CSR_STRIDE);
    int beg = gid * CSR_STRIDE;
    int end = beg + n;
    const uint2* z2 = (const uint2*)z2s;
    float4 acc = {0.f, 0.f, 0.f, 0.f};
    int e = beg;
    for (; e + 7 < end; e += 8) {
        uint2 tv[8];
#pragma unroll
        for (int q = 0; q < 8; ++q) {
            int s = csr_pad[e + q];
            tv[q] = z2[(size_t)s * 10 + li];
        }
#pragma unroll
        for (int q = 0; q < 8; ++q) {
            acc.x += bflo(tv[q].x); acc.y += bfhi(tv[q].x);
            acc.z += bflo(tv[q].y); acc.w += bfhi(tv[q].y);
        }
    }
    if (e + 3 < end) {
        uint2 tv[4];
#pragma unroll
        for (int q = 0; q < 4; ++q) {
            int s = csr_pad[e + q];
            tv[q] = z2[(size_t)s * 10 + li];
        }
#pragma unroll
        for (int q = 0; q < 4; ++q) {
            acc.x += bflo(tv[q].x); acc.y += bfhi(tv[q].x);
            acc.z += bflo(tv[q].y); acc.w += bfhi(tv[q].y);
        }
        e += 4;
    }
    for (; e < end; ++e) {
        int s = csr_pad[e];
        uint2 t0 = z2[(size_t)s * 10 + li];
        acc.x += bflo(t0.x); acc.y += bfhi(t0.x);
        acc.z += bflo(t0.y); acc.w += bfhi(t0.y);
    }
    float inv = 1.0f / fmaxf((float)n, 1.0f);
    float4 p = ((const float4*)p2)[(size_t)gid * 10 + li];
    float4 bb = ((const float4*)b2)[li];
    float4 r;
    r.x = fmaf(acc.x, inv, p.x + bb.x);
    r.y = fmaf(acc.y, inv, p.y + bb.y);
    r.z = fmaf(acc.z, inv, p.z + bb.z);
    r.w = fmaf(acc.w, inv, p.w + bb.w);
    ((float4*)out)[(size_t)gid * 10 + li] = r;
}

// ---------------------------------------------------------------------------
// Launch: 5 dispatches. ws layout (int units):
//   deg_i[50048] (memset 0)
//   csr_pad ushort[50000*64] = 1,600,000 ints
//   WfA u32[16384], WfB u32[5120]
//   x_bf16 u32[3200000]
//   agg1b u32[50048*64]
//   z2s ushort[50048*40] + p2 f32[50048*40]
// ---------------------------------------------------------------------------
extern "C" void kernel_launch(void* const* d_in, const int* in_sizes, int n_in,
                              void* d_out, int out_size, void* d_ws, size_t ws_size,
                              hipStream_t stream) {
    const float* x     = (const float*)d_in[0];
    const int*   ei    = (const int*)d_in[1];
    const float* W1l   = (const float*)d_in[2];
    const float* b1    = (const float*)d_in[3];
    const float* W1r   = (const float*)d_in[4];
    const float* gamma = (const float*)d_in[5];
    const float* beta  = (const float*)d_in[6];
    const float* rmean = (const float*)d_in[7];
    const float* rvar  = (const float*)d_in[8];
    const float* W2l   = (const float*)d_in[9];
    const float* b2    = (const float*)d_in[10];
    const float* W2r   = (const float*)d_in[11];
    float* out = (float*)d_out;

    int* deg_i              = (int*)d_ws;
    unsigned short* csr_pad = (unsigned short*)(deg_i + 50048);
    unsigned* WfA           = (unsigned*)(deg_i + 50048 + 1600000);
    unsigned* WfB           = WfA + 16384;
    unsigned* x_bf16        = WfB + 5120;
    unsigned* agg1b         = x_bf16 + 3200000;
    unsigned short* z2s     = (unsigned short*)(agg1b + (size_t)50048 * 64);
    float* p2               = (float*)(z2s + (size_t)50048 * 40);

    const int* src = ei;
    const int* dst = ei + N_EDGES;

    hipMemsetAsync(deg_i, 0, (size_t)50048 * sizeof(int), stream);

    degprep_kernel<<<CSR_B + WPACK_B + XPACK_B, 256, 0, stream>>>(
        src, dst, deg_i, csr_pad, W1l, W1r, W2l, W2r, x, WfA, WfB, x_bf16);

    gather1_kernel<<<(N_NODES + 15) / 16, 256, 0, stream>>>(csr_pad, deg_i, x_bf16, agg1b);

    gemm_fused_kernel<<<(N_NODES + 63) / 64, 256, 0, stream>>>(
        agg1b, x_bf16, WfA, WfB, b1, gamma, beta, rmean, rvar, z2s, p2);

    gather2_kernel<<<(N_NODES + 24) / 25, 256, 0, stream>>>(csr_pad, deg_i, z2s, p2, b2, out);
}